// Round 1
// baseline (67.019 us; speedup 1.0000x reference)
//
#include <hip/hip_runtime.h>

// Downsample (upfirdn2d, up=1, down=2, pad=(1,1)) with 4x4 FIR kernel.
// x: (8,128,256,256) f32 -> out: (8,128,128,128) f32.
//
// Layout: one wave (64 lanes) computes one full output row (128 px, 2/lane).
// Lane loads an aligned float4 of the input row (cols 4t..4t+3); halo cols
// 4t-1 / 4t+4 come from neighbor lanes via shuffles. A wave walks a strip of
// output rows, keeping the bottom 2 input rows of the 4-row window in
// registers (stride-2 windows overlap by 2 rows) -> 2 row-loads per output
// row = unique-data traffic.

constexpr int HI = 256, WI = 256, HO = 128, WO = 128;
constexpr int ROWS_PER_WAVE = 16;
constexpr int STRIPS = HO / ROWS_PER_WAVE;   // 8
constexpr int WAVES_PER_BLOCK = 4;           // 256 threads

struct Row {
    float4 v;   // input cols 4*lane .. 4*lane+3
    float l;    // input col 4*lane-1  (0 at left edge)
    float r;    // input col 4*lane+4  (0 at right edge)
};

__device__ inline Row load_row(const float* __restrict__ xp, int r, int lane) {
    Row R;
    float4 v;
    if (r >= 0 && r < HI) {
        v = *reinterpret_cast<const float4*>(xp + (size_t)r * WI + lane * 4);
    } else {
        v = make_float4(0.f, 0.f, 0.f, 0.f);
    }
    R.v = v;
    float lf = __shfl_up(v.w, 1, 64);
    if (lane == 0) lf = 0.f;
    float rg = __shfl_down(v.x, 1, 64);
    if (lane == 63) rg = 0.f;
    R.l = lf;
    R.r = rg;
    return R;
}

__global__ __launch_bounds__(256) void downsample_kernel(
        const float* __restrict__ x,
        const float* __restrict__ kern,
        float* __restrict__ out,
        int nplanes) {
    const int lane = threadIdx.x & 63;
    const int wv = threadIdx.x >> 6;
    const int gw = blockIdx.x * WAVES_PER_BLOCK + wv;  // global wave id
    const int plane = gw / STRIPS;
    const int strip = gw % STRIPS;
    if (plane >= nplanes) return;
    const int oh0 = strip * ROWS_PER_WAVE;

    // flipped FIR kernel (true convolution): w[i][j] = kern[3-i][3-j]
    float w[4][4];
#pragma unroll
    for (int i = 0; i < 4; ++i)
#pragma unroll
        for (int j = 0; j < 4; ++j)
            w[i][j] = kern[(3 - i) * 4 + (3 - j)];

    const float* xp = x + (size_t)plane * HI * WI;
    float* op = out + (size_t)plane * HO * WO;

    // window for output row oh: input rows 2oh-1 .. 2oh+2
    // carry rows = first two of current window
    Row r0 = load_row(xp, 2 * oh0 - 1, lane);
    Row r1 = load_row(xp, 2 * oh0, lane);

#pragma unroll 4
    for (int oh = oh0; oh < oh0 + ROWS_PER_WAVE; ++oh) {
        Row r2 = load_row(xp, 2 * oh + 1, lane);
        Row r3 = load_row(xp, 2 * oh + 2, lane);

        float a0 = 0.f, a1 = 0.f;
#define ACC(R, i)                                                          \
        a0 = fmaf(w[i][0], R.l,   a0); a0 = fmaf(w[i][1], R.v.x, a0);      \
        a0 = fmaf(w[i][2], R.v.y, a0); a0 = fmaf(w[i][3], R.v.z, a0);      \
        a1 = fmaf(w[i][0], R.v.y, a1); a1 = fmaf(w[i][1], R.v.z, a1);      \
        a1 = fmaf(w[i][2], R.v.w, a1); a1 = fmaf(w[i][3], R.r,   a1);
        ACC(r0, 0)
        ACC(r1, 1)
        ACC(r2, 2)
        ACC(r3, 3)
#undef ACC

        *reinterpret_cast<float2*>(op + (size_t)oh * WO + 2 * lane) =
            make_float2(a0, a1);

        // roll: bottom 2 rows of this window are top 2 of the next
        r0 = r2;
        r1 = r3;
    }
}

extern "C" void kernel_launch(void* const* d_in, const int* in_sizes, int n_in,
                              void* d_out, int out_size, void* d_ws, size_t ws_size,
                              hipStream_t stream) {
    const float* x = (const float*)d_in[0];
    const float* kern = (const float*)d_in[1];
    float* out = (float*)d_out;

    const int nplanes = in_sizes[0] / (HI * WI);   // 8*128 = 1024
    const int total_waves = nplanes * STRIPS;       // 8192
    const int blocks = (total_waves + WAVES_PER_BLOCK - 1) / WAVES_PER_BLOCK;

    downsample_kernel<<<blocks, WAVES_PER_BLOCK * 64, 0, stream>>>(
        x, kern, out, nplanes);
}

// Round 3
// 58.060 us; speedup vs baseline: 1.1543x; 1.1543x over previous
//
#include <hip/hip_runtime.h>

// Downsample (upfirdn2d, up=1, down=2, pad=(1,1)) with 4x4 FIR kernel.
// x: (8,128,256,256) f32 -> out: (8,128,128,128) f32.
//
// One wave (64 lanes) computes one full output row (128 px, 2/lane).
// Lane loads an aligned float4 of the input row (cols 4t..4t+3); halo cols
// 4t-1 / 4t+4 come from neighbor lanes via shuffles. A wave walks a strip of
// 32 output rows, keeping the bottom 2 input rows of the 4-row window in
// registers (stride-2 windows overlap by 2 rows) -> 2 row-loads per output
// row = unique-data traffic (+3.1% strip halo).
// Output stored nontemporal (never re-read) to keep L2 for input halos.

constexpr int HI = 256, WI = 256, HO = 128, WO = 128;
constexpr int ROWS_PER_WAVE = 32;
constexpr int STRIPS = HO / ROWS_PER_WAVE;   // 4
constexpr int WAVES_PER_BLOCK = 4;           // 256 threads

typedef float f32x2 __attribute__((ext_vector_type(2)));  // storable by builtin

struct Row {
    float4 v;   // input cols 4*lane .. 4*lane+3
    float l;    // input col 4*lane-1  (0 at left edge)
    float r;    // input col 4*lane+4  (0 at right edge)
};

__device__ inline Row load_row(const float* __restrict__ xp, int r, int lane) {
    Row R;
    float4 v;
    if (r >= 0 && r < HI) {
        v = *reinterpret_cast<const float4*>(xp + (size_t)r * WI + lane * 4);
    } else {
        v = make_float4(0.f, 0.f, 0.f, 0.f);
    }
    R.v = v;
    float lf = __shfl_up(v.w, 1, 64);
    if (lane == 0) lf = 0.f;
    float rg = __shfl_down(v.x, 1, 64);
    if (lane == 63) rg = 0.f;
    R.l = lf;
    R.r = rg;
    return R;
}

__global__ __launch_bounds__(256) void downsample_kernel(
        const float* __restrict__ x,
        const float* __restrict__ kern,
        float* __restrict__ out,
        int nplanes) {
    const int lane = threadIdx.x & 63;
    const int wv = threadIdx.x >> 6;
    const int gw = blockIdx.x * WAVES_PER_BLOCK + wv;  // global wave id
    const int plane = gw / STRIPS;
    const int strip = gw % STRIPS;
    if (plane >= nplanes) return;
    const int oh0 = strip * ROWS_PER_WAVE;

    // flipped FIR kernel (true convolution): w[i][j] = kern[3-i][3-j]
    float w[4][4];
#pragma unroll
    for (int i = 0; i < 4; ++i)
#pragma unroll
        for (int j = 0; j < 4; ++j)
            w[i][j] = kern[(3 - i) * 4 + (3 - j)];

    const float* xp = x + (size_t)plane * HI * WI;
    float* op = out + (size_t)plane * HO * WO;

    // window for output row oh: input rows 2oh-1 .. 2oh+2
    Row r0 = load_row(xp, 2 * oh0 - 1, lane);
    Row r1 = load_row(xp, 2 * oh0, lane);

#pragma unroll 4
    for (int oh = oh0; oh < oh0 + ROWS_PER_WAVE; ++oh) {
        Row r2 = load_row(xp, 2 * oh + 1, lane);
        Row r3 = load_row(xp, 2 * oh + 2, lane);

        float a0 = 0.f, a1 = 0.f;
#define ACC(R, i)                                                          \
        a0 = fmaf(w[i][0], R.l,   a0); a0 = fmaf(w[i][1], R.v.x, a0);      \
        a0 = fmaf(w[i][2], R.v.y, a0); a0 = fmaf(w[i][3], R.v.z, a0);      \
        a1 = fmaf(w[i][0], R.v.y, a1); a1 = fmaf(w[i][1], R.v.z, a1);      \
        a1 = fmaf(w[i][2], R.v.w, a1); a1 = fmaf(w[i][3], R.r,   a1);
        ACC(r0, 0)
        ACC(r1, 1)
        ACC(r2, 2)
        ACC(r3, 3)
#undef ACC

        f32x2 res = {a0, a1};
        __builtin_nontemporal_store(res,
            reinterpret_cast<f32x2*>(op + (size_t)oh * WO + 2 * lane));

        // roll: bottom 2 rows of this window are top 2 of the next
        r0 = r2;
        r1 = r3;
    }
}

extern "C" void kernel_launch(void* const* d_in, const int* in_sizes, int n_in,
                              void* d_out, int out_size, void* d_ws, size_t ws_size,
                              hipStream_t stream) {
    const float* x = (const float*)d_in[0];
    const float* kern = (const float*)d_in[1];
    float* out = (float*)d_out;

    const int nplanes = in_sizes[0] / (HI * WI);   // 8*128 = 1024
    const int total_waves = nplanes * STRIPS;       // 4096
    const int blocks = (total_waves + WAVES_PER_BLOCK - 1) / WAVES_PER_BLOCK;

    downsample_kernel<<<blocks, WAVES_PER_BLOCK * 64, 0, stream>>>(
        x, kern, out, nplanes);
}